// Round 6
// baseline (115.413 us; speedup 1.0000x reference)
//
#include <hip/hip_runtime.h>
#include <math.h>

// Problem constants (from reference setup_inputs)
static constexpr int B_ = 32;    // batch
static constexpr int T_ = 336;   // time
static constexpr int C_ = 7;     // channels (m)
static constexpr int PB = 140;   // 4 banks * 35 cols per batch row
// d_out layout: out[32*10] | dists[32*140] | probs[32*140] | loss[1]
static constexpr int DIST_OFF = 320;
static constexpr int PROB_OFF = 320 + 4480;   // 4800
static constexpr int LOSS_OFF = 9280;

static constexpr int GRID = 32 * 7 * 2;   // 448 blocks: (b, m, half)

// w staged in LDS transposed, [j][n] stride 5, each bank 16B-aligned.
// half 0: bank0 @0 (170), bank1 @172 (340), bank2 @512 (505)
// half 1: bank2 @0 (505), bank3 @508 (840)
static constexpr int WT_FLOATS = 1352;

// ---------------------------------------------------------------------------
// Chunk-batched distance scan. Per chunk of JC j's: hoist 5*JC/4 float4
// broadcast reads of w + (W+JC-1) b32 reads of x as INDEPENDENT loads (one
// lgkmcnt wait per chunk), then JC*W*5 fabs-accumulates. No per-j dependent
// LDS chain. Publishes min-of-sum via global atomicMin (uint bits).
// ---------------------------------------------------------------------------
template <int L, int W, int JC>
__device__ __forceinline__ void dist_task(const float* __restrict__ xs,
                                          const float* __restrict__ wT,  // 16B-aligned
                                          int ws, int count,
                                          unsigned* __restrict__ gmin,
                                          int slotBase)   // (bank*35+m)*32+b
{
    const int lane = threadIdx.x & 63;
    int start = ws + W * lane;
    const int smax = ws + count - W;          // count >= W for all tasks
    if (start > smax) start = smax;           // clamped lanes recompute dups

    float acc[5][W];
    #pragma unroll
    for (int n = 0; n < 5; ++n)
        #pragma unroll
        for (int k = 0; k < W; ++k) acc[n][k] = 0.f;

    constexpr int NV = 5 * JC / 4;            // float4s per w-chunk
    const float4* __restrict__ w4 = reinterpret_cast<const float4*>(wT);

    for (int c = 0; c < L / JC; ++c) {
        const int j0 = c * JC;
        float4 wr4[NV];
        #pragma unroll
        for (int q = 0; q < NV; ++q) wr4[q] = w4[c * NV + q];   // broadcast b128
        const float* wr = reinterpret_cast<const float*>(wr4);

        float xv[W + JC - 1];
        #pragma unroll
        for (int u = 0; u < W + JC - 1; ++u) xv[u] = xs[start + j0 + u];

        #pragma unroll
        for (int jj = 0; jj < JC; ++jj) {
            #pragma unroll
            for (int k = 0; k < W; ++k) {
                const float xk = xv[jj + k];
                #pragma unroll
                for (int n = 0; n < 5; ++n)
                    acc[n][k] += fabsf(xk - wr[jj * 5 + n]);
            }
        }
    }
    // tail j's (L % JC): 34%4=2, 101%4=1, others 0
    #pragma unroll
    for (int j = (L / JC) * JC; j < L; ++j) {
        float wr[5];
        #pragma unroll
        for (int n = 0; n < 5; ++n) wr[n] = wT[j * 5 + n];
        #pragma unroll
        for (int k = 0; k < W; ++k) {
            const float xk = xs[start + j + k];
            #pragma unroll
            for (int n = 0; n < 5; ++n) acc[n][k] += fabsf(xk - wr[n]);
        }
    }

    #pragma unroll
    for (int n = 0; n < 5; ++n) {
        float bn = acc[n][0];
        #pragma unroll
        for (int k = 1; k < W; ++k) bn = fminf(bn, acc[n][k]);
        #pragma unroll
        for (int off = 32; off; off >>= 1)
            bn = fminf(bn, __shfl_down(bn, off, 64));
        if (lane == 0)
            atomicMin(&gmin[slotBase + n * 224], __float_as_uint(bn));
    }
}

// ---------------------------------------------------------------------------
// Grid: (b, m, half). Wave tasks (balanced to ~1700-2040 lane-ops each):
//   half 0: bank0[0,303)W5 | bank1[0,192)W3 | bank1[192,269)W3 | bank2[0,128)W2
//   half 1: bank2[128,236)W2 | bank3[0,64)W1 | bank3[64,128)W1 | bank3[128,169)W1
// Last block (election) converts min-sums -> dists/probs, GEMV, loss.
// ---------------------------------------------------------------------------
__global__ __launch_bounds__(256)
void k_fused(const float* __restrict__ x,
             const float* __restrict__ w0, const float* __restrict__ w1,
             const float* __restrict__ w2, const float* __restrict__ w3,
             const float* __restrict__ W_out,
             float* __restrict__ out,
             unsigned* __restrict__ gmin,      // d_ws[0:4480]
             unsigned* __restrict__ counter)   // d_ws[4480]
{
    __shared__ float xs[344];                       // 336 + pad
    __shared__ __align__(16) float wT[WT_FLOATS];   // transposed w, stride 5
    __shared__ float red[8];
    __shared__ int   lastFlag;
    __shared__ float pS[32 * PB];                   // epilogue GEMV staging

    const int bid  = blockIdx.x;               // 448
    const int b    = bid / 14;
    const int rem  = bid % 14;
    const int m    = rem >> 1;
    const int h    = rem & 1;
    const int tid  = threadIdx.x;
    const int lane = tid & 63;
    const int wv   = tid >> 6;

    // ---- load channel row x[b,:,m] (stride C_), fused sum/sumsq ----
    const float* __restrict__ xb = x + (size_t)b * T_ * C_ + m;
    float s = 0.f, q = 0.f;
    for (int t = tid; t < 344; t += 256) {
        const float v = (t < T_) ? xb[(size_t)t * C_] : 0.f;
        xs[t] = v;
        s += v; q += v * v;
    }

    // ---- stage w transposed: wT[off + j*5 + n] = w[n][m][j] ----
    {
        const float* srcA; const float* srcB; const float* srcC;
        int LA, LB, LC, oA, oB, oC;
        if (h == 0) { srcA = w0 + m * 34;  LA = 34;  oA = 0;
                      srcB = w1 + m * 68;  LB = 68;  oB = 172;
                      srcC = w2 + m * 101; LC = 101; oC = 512; }
        else        { srcA = w2 + m * 101; LA = 101; oA = 0;
                      srcB = w3 + m * 168; LB = 168; oB = 508;
                      srcC = nullptr;      LC = 0;   oC = 0; }
        for (int i = tid; i < 5 * LA; i += 256) {
            int n = i / LA, j = i - n * LA;
            wT[oA + j * 5 + n] = srcA[(size_t)n * C_ * LA + j];
        }
        for (int i = tid; i < 5 * LB; i += 256) {
            int n = i / LB, j = i - n * LB;
            wT[oB + j * 5 + n] = srcB[(size_t)n * C_ * LB + j];
        }
        for (int i = tid; i < 5 * LC; i += 256) {
            int n = i / LC, j = i - n * LC;
            wT[oC + j * 5 + n] = srcC[(size_t)n * C_ * LC + j];
        }
    }

    // ---- single-pass normalize (ddof=1): var = (q - s^2/T)/(T-1) ----
    #pragma unroll
    for (int off = 32; off; off >>= 1) {
        s += __shfl_down(s, off, 64);
        q += __shfl_down(q, off, 64);
    }
    if (lane == 0) { red[wv] = s; red[4 + wv] = q; }
    __syncthreads();
    const float S  = red[0] + red[1] + red[2] + red[3];
    const float Q  = red[4] + red[5] + red[6] + red[7];
    const float mu = S / (float)T_;
    const float var = fmaxf((Q - S * mu) / (float)(T_ - 1), 0.f);
    const float inv = 1.f / (sqrtf(var) + 1e-8f);
    for (int t = tid; t < T_; t += 256) xs[t] = (xs[t] - mu) * inv;
    __syncthreads();

    // ---- balanced wave-tasks ----
    const int sb0 = (0 * 35 + m) * 32 + b;
    const int sb1 = (1 * 35 + m) * 32 + b;
    const int sb2 = (2 * 35 + m) * 32 + b;
    const int sb3 = (3 * 35 + m) * 32 + b;
    if (h == 0) {
        switch (wv) {
            case 0: dist_task<34, 5, 4>(xs, wT,         0, 303, gmin, sb0); break;
            case 1: dist_task<68, 3, 4>(xs, wT + 172,   0, 192, gmin, sb1); break;
            case 2: dist_task<68, 3, 4>(xs, wT + 172, 192,  77, gmin, sb1); break;
            default:dist_task<101,2, 4>(xs, wT + 512,   0, 128, gmin, sb2); break;
        }
    } else {
        switch (wv) {
            case 0: dist_task<101,2, 4>(xs, wT,       128, 108, gmin, sb2); break;
            case 1: dist_task<168,1, 8>(xs, wT + 508,   0,  64, gmin, sb3); break;
            case 2: dist_task<168,1, 8>(xs, wT + 508,  64,  64, gmin, sb3); break;
            default:dist_task<168,1, 8>(xs, wT + 508, 128,  41, gmin, sb3); break;
        }
    }

    // ---- last-block election ----
    __syncthreads();
    if (tid == 0) {
        __threadfence();
        lastFlag = (atomicAdd(counter, 1u) == (unsigned)(GRID - 1)) ? 1 : 0;
    }
    __syncthreads();
    if (!lastFlag) return;

    // ================= epilogue (one block) =================
    __threadfence();
    for (int i = tid; i < 32 * PB; i += 256) {
        const int col = i >> 5;           // 0..139
        const int bb  = i & 31;           // 0..31
        const unsigned u = __hip_atomic_load(&gmin[i], __ATOMIC_RELAXED,
                                             __HIP_MEMORY_SCOPE_AGENT);
        const int bk = col / 35;
        const int l  = (bk == 0) ? 34 : (bk == 1) ? 68 : (bk == 2) ? 101 : 168;
        const float d = __uint_as_float(u) / (float)l;   // min-sum -> min-mean
        const float p = expf(-d * d);                    // EPS_GATE = 1.0
        out[DIST_OFF + bb * PB + col] = d;
        out[PROB_OFF + bb * PB + col] = p;
        pS[bb * PB + col] = p;
    }
    __syncthreads();

    // out[b,k] = probs[b,:] . W_out[k,:]
    for (int i = tid; i < 320; i += 256) {
        const int bb = i / 10, k = i % 10;
        const float* __restrict__ pb = pS + bb * PB;
        const float* __restrict__ wk = W_out + k * PB;
        float acc = 0.f;
        #pragma unroll 4
        for (int j = 0; j < PB; ++j) acc += pb[j] * wk[j];
        out[bb * 10 + k] = acc;
    }

    // loss = 0.1 * mean|W_out| (1400 elems)
    float ls = 0.f;
    for (int j = tid; j < 1400; j += 256) ls += fabsf(W_out[j]);
    #pragma unroll
    for (int off = 32; off; off >>= 1) ls += __shfl_down(ls, off, 64);
    if (lane == 0) red[wv] = ls;
    __syncthreads();
    if (tid == 0)
        out[LOSS_OFF] = 0.1f * (red[0] + red[1] + red[2] + red[3]) / 1400.0f;
}

extern "C" void kernel_launch(void* const* d_in, const int* in_sizes, int n_in,
                              void* d_out, int out_size, void* d_ws, size_t ws_size,
                              hipStream_t stream)
{
    const float* x     = (const float*)d_in[0];
    const float* w0    = (const float*)d_in[1];
    const float* w1    = (const float*)d_in[2];
    const float* w2    = (const float*)d_in[3];
    const float* w3    = (const float*)d_in[4];
    const float* W_out = (const float*)d_in[5];
    float*    out  = (float*)d_out;
    unsigned* gmin = (unsigned*)d_ws;            // 4480 slots
    unsigned* cnt  = gmin + 32 * PB;             // 1 slot

    hipMemsetAsync(gmin, 0xFF, 32 * PB * sizeof(unsigned), stream);
    hipMemsetAsync(cnt, 0, sizeof(unsigned), stream);
    hipLaunchKernelGGL(k_fused, dim3(GRID), dim3(256), 0, stream,
                       x, w0, w1, w2, w3, W_out, out, gmin, cnt);
}

// Round 7
// 104.578 us; speedup vs baseline: 1.1036x; 1.1036x over previous
//
#include <hip/hip_runtime.h>
#include <math.h>

// Problem constants (from reference setup_inputs)
static constexpr int B_ = 32;    // batch
static constexpr int T_ = 336;   // time
static constexpr int C_ = 7;     // channels (m)
static constexpr int PB = 140;   // 4 banks * 35 cols per batch row
// d_out layout: out[32*10] | dists[32*140] | probs[32*140] | loss[1]
static constexpr int DIST_OFF = 320;
static constexpr int PROB_OFF = 320 + 4480;   // 4800
static constexpr int LOSS_OFF = 9280;

static constexpr int GRID = 32 * 7 * 2;   // 448 blocks: (b, m, half)

__device__ __forceinline__ float bcast_lane(float v, int j)
{   // wave-uniform j -> v_readlane_b32 (SGPR result). No memory op.
    return __uint_as_float(__builtin_amdgcn_readlane(__float_as_uint(v), j));
}

// ---------------------------------------------------------------------------
// Register-resident distance scan. wreg[c][n] = w[n][m][c*64+lane]; inner loop
// per j: 1 sliding ds_read_b32 of x + 5 v_readlane broadcasts of w + 10*W
// VALU. No LDS/SMEM dependency chain. Publishes min-of-sum via global
// atomicMin (uint bits; non-negative floats so uint order == float order).
// ---------------------------------------------------------------------------
template <int L, int W, int CH>
__device__ __forceinline__ void dist_task(const float* __restrict__ xs,
                                          const float* __restrict__ wg,  // global: w + m*L
                                          int ws, int count,
                                          unsigned* __restrict__ gmin,
                                          int slotBase)   // (bank*35+m)*32+b
{
    const int lane = threadIdx.x & 63;

    // preload this wave's w slice into registers (coalesced 64-lane loads)
    float wreg[CH][5];
    #pragma unroll
    for (int c = 0; c < CH; ++c) {
        int j = c * 64 + lane; if (j >= L) j = L - 1;   // clamp (unused lanes)
        #pragma unroll
        for (int n = 0; n < 5; ++n)
            wreg[c][n] = wg[(size_t)n * (C_ * L) + j];
    }

    int start = ws + W * lane;
    const int smax = ws + count - W;          // count >= W for all tasks
    if (start > smax) start = smax;           // clamped lanes recompute dups

    float acc[5][W];
    #pragma unroll
    for (int n = 0; n < 5; ++n)
        #pragma unroll
        for (int k = 0; k < W; ++k) acc[n][k] = 0.f;

    float xv[W];
    #pragma unroll
    for (int k = 0; k < W; ++k) xv[k] = xs[start + k];

    #pragma unroll
    for (int c = 0; c < CH; ++c) {
        const int jend = (L - c * 64 < 64) ? (L - c * 64) : 64;  // const-folds
        #pragma unroll 8
        for (int j = 0; j < jend; ++j) {
            const float wa = bcast_lane(wreg[c][0], j);
            const float wb = bcast_lane(wreg[c][1], j);
            const float wc = bcast_lane(wreg[c][2], j);
            const float wd = bcast_lane(wreg[c][3], j);
            const float we = bcast_lane(wreg[c][4], j);
            #pragma unroll
            for (int k = 0; k < W; ++k) {
                const float xk = xv[k];
                acc[0][k] += fabsf(xk - wa);
                acc[1][k] += fabsf(xk - wb);
                acc[2][k] += fabsf(xk - wc);
                acc[3][k] += fabsf(xk - wd);
                acc[4][k] += fabsf(xk - we);
            }
            // slide one step (xs padded to 344; max index 336)
            #pragma unroll
            for (int k = 0; k < W - 1; ++k) xv[k] = xv[k + 1];
            xv[W - 1] = xs[start + (c * 64 + j) + W];
        }
    }

    #pragma unroll
    for (int n = 0; n < 5; ++n) {
        float bn = acc[n][0];
        #pragma unroll
        for (int k = 1; k < W; ++k) bn = fminf(bn, acc[n][k]);
        #pragma unroll
        for (int off = 32; off; off >>= 1)
            bn = fminf(bn, __shfl_down(bn, off, 64));
        if (lane == 0)
            atomicMin(&gmin[slotBase + n * 224], __float_as_uint(bn));
    }
}

// ---------------------------------------------------------------------------
// Grid: (b, m, half). Balanced wave tasks (~1700-2040 VALU lane-ops each):
//   half 0: bank0[0,303)W5 | bank1[0,192)W3 | bank1[192,269)W3 | bank2[0,128)W2
//   half 1: bank2[128,236)W2 | bank3[0,64)W1 | bank3[64,128)W1 | bank3[128,169)W1
// Last block (global election) converts min-sums -> dists/probs, GEMV, loss.
// ---------------------------------------------------------------------------
__global__ __launch_bounds__(256)
void k_fused(const float* __restrict__ x,
             const float* __restrict__ w0, const float* __restrict__ w1,
             const float* __restrict__ w2, const float* __restrict__ w3,
             const float* __restrict__ W_out,
             float* __restrict__ out,
             unsigned* __restrict__ gmin,      // d_ws[0:4480]
             unsigned* __restrict__ counter)   // d_ws[4480]
{
    __shared__ float xs[344];                  // 336 + slide pad
    __shared__ float red[8];
    __shared__ int   lastFlag;
    __shared__ float pS[32 * PB];              // epilogue GEMV staging

    const int bid  = blockIdx.x;               // 448
    const int b    = bid / 14;
    const int rem  = bid % 14;
    const int m    = rem >> 1;
    const int h    = rem & 1;
    const int tid  = threadIdx.x;
    const int lane = tid & 63;
    const int wv   = tid >> 6;

    // ---- load channel row x[b,:,m] (stride C_), fused sum/sumsq ----
    const float* __restrict__ xb = x + (size_t)b * T_ * C_ + m;
    float s = 0.f, q = 0.f;
    for (int t = tid; t < 344; t += 256) {
        const float v = (t < T_) ? xb[(size_t)t * C_] : 0.f;
        xs[t] = v;
        s += v; q += v * v;
    }

    // ---- single-pass normalize (ddof=1): var = (q - s^2/T)/(T-1) ----
    #pragma unroll
    for (int off = 32; off; off >>= 1) {
        s += __shfl_down(s, off, 64);
        q += __shfl_down(q, off, 64);
    }
    if (lane == 0) { red[wv] = s; red[4 + wv] = q; }
    __syncthreads();
    const float S   = red[0] + red[1] + red[2] + red[3];
    const float Q   = red[4] + red[5] + red[6] + red[7];
    const float mu  = S / (float)T_;
    const float var = fmaxf((Q - S * mu) / (float)(T_ - 1), 0.f);
    const float inv = 1.f / (sqrtf(var) + 1e-8f);
    for (int t = tid; t < T_; t += 256) xs[t] = (xs[t] - mu) * inv;
    __syncthreads();

    // ---- balanced wave-tasks (w read from GLOBAL into registers) ----
    const int sb0 = (0 * 35 + m) * 32 + b;
    const int sb1 = (1 * 35 + m) * 32 + b;
    const int sb2 = (2 * 35 + m) * 32 + b;
    const int sb3 = (3 * 35 + m) * 32 + b;
    if (h == 0) {
        switch (wv) {
            case 0: dist_task<34, 5, 1>(xs, w0 + m * 34,    0, 303, gmin, sb0); break;
            case 1: dist_task<68, 3, 2>(xs, w1 + m * 68,    0, 192, gmin, sb1); break;
            case 2: dist_task<68, 3, 2>(xs, w1 + m * 68,  192,  77, gmin, sb1); break;
            default:dist_task<101,2, 2>(xs, w2 + m * 101,   0, 128, gmin, sb2); break;
        }
    } else {
        switch (wv) {
            case 0: dist_task<101,2, 2>(xs, w2 + m * 101, 128, 108, gmin, sb2); break;
            case 1: dist_task<168,1, 3>(xs, w3 + m * 168,   0,  64, gmin, sb3); break;
            case 2: dist_task<168,1, 3>(xs, w3 + m * 168,  64,  64, gmin, sb3); break;
            default:dist_task<168,1, 3>(xs, w3 + m * 168, 128,  41, gmin, sb3); break;
        }
    }

    // ---- last-block election ----
    __syncthreads();
    if (tid == 0) {
        __threadfence();
        lastFlag = (atomicAdd(counter, 1u) == (unsigned)(GRID - 1)) ? 1 : 0;
    }
    __syncthreads();
    if (!lastFlag) return;

    // ================= epilogue (one block) =================
    __threadfence();
    for (int i = tid; i < 32 * PB; i += 256) {
        const int col = i >> 5;           // 0..139
        const int bb  = i & 31;           // 0..31
        const unsigned u = __hip_atomic_load(&gmin[i], __ATOMIC_RELAXED,
                                             __HIP_MEMORY_SCOPE_AGENT);
        const int bk = col / 35;
        const int l  = (bk == 0) ? 34 : (bk == 1) ? 68 : (bk == 2) ? 101 : 168;
        const float d = __uint_as_float(u) / (float)l;   // min-sum -> min-mean
        const float p = expf(-d * d);                    // EPS_GATE = 1.0
        out[DIST_OFF + bb * PB + col] = d;
        out[PROB_OFF + bb * PB + col] = p;
        pS[bb * PB + col] = p;
    }
    __syncthreads();

    // out[b,k] = probs[b,:] . W_out[k,:]
    for (int i = tid; i < 320; i += 256) {
        const int bb = i / 10, k = i % 10;
        const float* __restrict__ pb = pS + bb * PB;
        const float* __restrict__ wk = W_out + k * PB;
        float acc = 0.f;
        #pragma unroll 4
        for (int j = 0; j < PB; ++j) acc += pb[j] * wk[j];
        out[bb * 10 + k] = acc;
    }

    // loss = 0.1 * mean|W_out| (1400 elems)
    float ls = 0.f;
    for (int j = tid; j < 1400; j += 256) ls += fabsf(W_out[j]);
    #pragma unroll
    for (int off = 32; off; off >>= 1) ls += __shfl_down(ls, off, 64);
    if (lane == 0) red[wv] = ls;
    __syncthreads();
    if (tid == 0)
        out[LOSS_OFF] = 0.1f * (red[0] + red[1] + red[2] + red[3]) / 1400.0f;
}

extern "C" void kernel_launch(void* const* d_in, const int* in_sizes, int n_in,
                              void* d_out, int out_size, void* d_ws, size_t ws_size,
                              hipStream_t stream)
{
    const float* x     = (const float*)d_in[0];
    const float* w0    = (const float*)d_in[1];
    const float* w1    = (const float*)d_in[2];
    const float* w2    = (const float*)d_in[3];
    const float* w3    = (const float*)d_in[4];
    const float* W_out = (const float*)d_in[5];
    float*    out  = (float*)d_out;
    unsigned* gmin = (unsigned*)d_ws;            // 4480 slots
    unsigned* cnt  = gmin + 32 * PB;             // 1 slot

    hipMemsetAsync(gmin, 0xFF, 32 * PB * sizeof(unsigned), stream);
    hipMemsetAsync(cnt, 0, sizeof(unsigned), stream);
    hipLaunchKernelGGL(k_fused, dim3(GRID), dim3(256), 0, stream,
                       x, w0, w1, w2, w3, W_out, out, gmin, cnt);
}